// Round 5
// baseline (117.932 us; speedup 1.0000x reference)
//
#include <hip/hip_runtime.h>
#include <hip/hip_bf16.h>
#include <math.h>

#define DEV __device__ __forceinline__

typedef __attribute__((ext_vector_type(4))) float f32x4;
typedef __attribute__((ext_vector_type(8))) short bf16x8;

DEV unsigned short f2bf(float v) {
    __hip_bfloat16 h = __float2bfloat16(v);
    return *reinterpret_cast<unsigned short*>(&h);
}

// ============================ prep: weight transposes ============================
// w2b: bf16, index i = ((tap*2+kk)*4 + fq)*128 + oc*8 + j  -> W2[oc][kk*32+fq*8+j][tap]
__global__ void prep_kernel(const float* __restrict__ w2,   // (16,64,3,3)
                            const float* __restrict__ fc1w, // (64,196)
                            const float* __restrict__ fc2w, // (128,64)
                            const float* __restrict__ fc3w, // (64,128)
                            const float* __restrict__ fc4w, // (10,64)
                            unsigned short* __restrict__ w2b, // 9216 bf16
                            float* __restrict__ fc1t,        // (196,64)
                            float* __restrict__ fc2t,        // (64,128)
                            float* __restrict__ fc3t,        // (128,64)
                            float* __restrict__ fc4t)        // (64,10)
{
    int t = blockIdx.x * blockDim.x + threadIdx.x;
    int NT = gridDim.x * blockDim.x;
    for (int i = t; i < 9216; i += NT) {
        int j = i & 7, oc = (i >> 3) & 15, fq = (i >> 7) & 3, f = i >> 9;
        int tap = f >> 1, kk = f & 1;
        int ic = kk * 32 + fq * 8 + j;
        w2b[i] = f2bf(w2[(oc * 64 + ic) * 9 + tap]);
    }
    for (int i = t; i < 12544; i += NT) { int j = i / 196, k = i % 196; fc1t[k * 64 + j] = fc1w[i]; }
    for (int i = t; i < 8192;  i += NT) { int j = i / 64,  k = i % 64;  fc2t[k * 128 + j] = fc2w[i]; }
    for (int i = t; i < 8192;  i += NT) { int j = i / 128, k = i % 128; fc3t[k * 64 + j] = fc3w[i]; }
    for (int i = t; i < 640;   i += NT) { int j = i / 64,  k = i % 64;  fc4t[k * 10 + j] = fc4w[i]; }
}

// ============================ conv1 + relu + pool (NHWC bf16 out) ============================
// x:(2048,1,28,28) -> out1:(2048, 196 pos, 64 ch) bf16.
// 3 images/block (640 thr). thread = pooled position; window in VGPRs (8 x ds_read_b64,
// one time); weights via wave-uniform s_load; oc in 8 groups of 8, packed words have
// compile-time indices only (NO runtime-indexed array -> no scratch), store per group.
__global__ __launch_bounds__(640, 1) void conv1_kernel(
    const float* __restrict__ x, const float* __restrict__ w1,
    const float* __restrict__ b1, unsigned short* __restrict__ out1)
{
    __shared__ float pin[3][30][34];   // zero-padded, row stride 34 (even -> b64-aligned)
    int t = threadIdx.x;
    int n0 = blockIdx.x * 3;

    for (int i = t; i < 3060; i += 640) ((float*)pin)[i] = 0.f;
    __syncthreads();
    for (int i = t; i < 2352; i += 640) {
        int img = i / 784, p = i - img * 784;
        int n = n0 + img;
        if (n < 2048) pin[img][p / 28 + 1][p % 28 + 1] = x[n * 784 + p];
    }
    __syncthreads();

    int img = t / 208, r = t - img * 208;
    bool act = (img < 3) && (r < 196) && (n0 + img < 2048);
    if (img > 2) img = 2;
    if (!act) r = 0;
    int py = r / 14, px = r - py * 14;

    // 4x4 window into registers (8 x ds_read_b64, all 8B-aligned)
    float p[4][4];
    const float* base = &pin[img][2 * py][2 * px];
    #pragma unroll
    for (int dy = 0; dy < 4; ++dy) {
        float2 lo = *reinterpret_cast<const float2*>(base + dy * 34);
        float2 hi = *reinterpret_cast<const float2*>(base + dy * 34 + 2);
        p[dy][0] = lo.x; p[dy][1] = lo.y; p[dy][2] = hi.x; p[dy][3] = hi.y;
    }

    unsigned short* op = out1 + ((size_t)(n0 + img) * 196 + r) * 64;

    #pragma unroll
    for (int g = 0; g < 8; ++g) {
        unsigned pk0, pk1, pk2, pk3;
        #pragma unroll
        for (int k = 0; k < 8; ++k) {
            int oc = g * 8 + k;
            float w0 = w1[oc * 9 + 0], w1v = w1[oc * 9 + 1], w2v = w1[oc * 9 + 2],
                  w3v = w1[oc * 9 + 3], w4v = w1[oc * 9 + 4], w5v = w1[oc * 9 + 5],
                  w6v = w1[oc * 9 + 6], w7v = w1[oc * 9 + 7], w8v = w1[oc * 9 + 8];
            float bb = b1[oc];
            float m = -INFINITY;
            #pragma unroll
            for (int dy = 0; dy < 2; ++dy)
                #pragma unroll
                for (int dx = 0; dx < 2; ++dx) {
                    float s = w0 *p[dy][dx]     + w1v*p[dy][dx+1]     + w2v*p[dy][dx+2]
                            + w3v*p[dy+1][dx]   + w4v*p[dy+1][dx+1]   + w5v*p[dy+1][dx+2]
                            + w6v*p[dy+2][dx]   + w7v*p[dy+2][dx+1]   + w8v*p[dy+2][dx+2];
                    m = fmaxf(m, s);
                }
            unsigned u = f2bf(fmaxf(m + bb, 0.f));
            // compile-time selection after full unroll -> pure register writes
            if (k == 0) pk0 = u;            else if (k == 1) pk0 |= u << 16;
            else if (k == 2) pk1 = u;       else if (k == 3) pk1 |= u << 16;
            else if (k == 4) pk2 = u;       else if (k == 5) pk2 |= u << 16;
            else if (k == 6) pk3 = u;       else             pk3 |= u << 16;
        }
        if (act) {
            uint4 v; v.x = pk0; v.y = pk1; v.z = pk2; v.w = pk3;
            reinterpret_cast<uint4*>(op)[g] = v;
        }
    }
}

// ============================ conv2 via MFMA (9 shifted GEMMs) + pool ============================
// out1 NHWC bf16 -> out2:(2048,16,7,7) f32.  1 image/block, 13 M-tiles over 4 waves.
__global__ __launch_bounds__(256, 4) void conv2_kernel(
    const unsigned short* __restrict__ out1, const unsigned short* __restrict__ w2b,
    const float* __restrict__ b2, float* __restrict__ out2)
{
    __shared__ unsigned short in_l[16384];   // 32 KB padded 16x16 grid x 64 ic, XOR-swizzled
    float* d_l = (float*)in_l;               // aliased pre-pool buffer [196][17] f32
    int t = threadIdx.x, lane = t & 63, fq = lane >> 4, fr = lane & 15, wv = t >> 6;
    int n = blockIdx.x;

    // B fragments straight from L2 (identical across blocks)
    bf16x8 bfrag[18];
    const bf16x8* wb = (const bf16x8*)w2b;
    #pragma unroll
    for (int f = 0; f < 18; ++f) bfrag[f] = wb[(f * 4 + fq) * 16 + fr];

    for (int i = t; i < 2048; i += 256) ((f32x4*)in_l)[i] = f32x4{0.f, 0.f, 0.f, 0.f};
    __syncthreads();

    const ushort2* src = (const ushort2*)(out1 + (size_t)n * 12544);
    for (int i = t; i < 6272; i += 256) {
        int pos = i >> 5, icp = i & 31;
        int y = pos / 14, xx = pos - y * 14;
        int grid = (y + 1) * 16 + (xx + 1);
        int byte = (grid * 128 + icp * 4) ^ ((grid & 7) << 4);
        *(ushort2*)((char*)in_l + byte) = src[i];
    }
    __syncthreads();

    for (int r = 0; r < 4; ++r) {
        int tile = r * 4 + wv;
        bool tv = tile < 13;
        f32x4 acc = {0.f, 0.f, 0.f, 0.f};
        int pd0 = tile * 16 + fq * 4;
        if (tv) {
            int pos = tile * 16 + fr; pos = pos > 195 ? 195 : pos;   // clamp tail tile
            int y = pos / 14, xx = pos - y * 14;
            int g0 = y * 16 + xx;
            int vb = g0 * 128 + fq * 16;
            #pragma unroll
            for (int ky = 0; ky < 3; ++ky)
                #pragma unroll
                for (int kx = 0; kx < 3; ++kx) {
                    int dg = ky * 16 + kx;
                    int msk = ((g0 + dg) & 7) << 4;
                    int lin = vb + dg * 128;
                    bf16x8 a0 = *(const bf16x8*)((const char*)in_l + (lin ^ msk));
                    acc = __builtin_amdgcn_mfma_f32_16x16x32_bf16(a0, bfrag[(ky * 3 + kx) * 2], acc, 0, 0, 0);
                    bf16x8 a1 = *(const bf16x8*)((const char*)in_l + ((lin | 64) ^ msk));
                    acc = __builtin_amdgcn_mfma_f32_16x16x32_bf16(a1, bfrag[(ky * 3 + kx) * 2 + 1], acc, 0, 0, 0);
                }
        }
        __syncthreads();                      // all reads of this round done
        if (tv) {
            #pragma unroll
            for (int reg = 0; reg < 4; ++reg) {
                int pd = pd0 + reg;
                if (pd < 196) d_l[pd * 17 + fr] = acc[reg];
            }
        }
        __syncthreads();                      // writes visible; ranges for next round disjoint
    }

    float* op = out2 + (size_t)n * 784;
    for (int i = t; i < 784; i += 256) {
        int oc = i & 15, p7 = i >> 4;
        int y7 = p7 / 7, x7 = p7 % 7;
        int p00 = (2 * y7) * 14 + 2 * x7;
        float m = fmaxf(fmaxf(d_l[p00 * 17 + oc], d_l[(p00 + 1) * 17 + oc]),
                        fmaxf(d_l[(p00 + 14) * 17 + oc], d_l[(p00 + 15) * 17 + oc]));
        op[oc * 49 + p7] = fmaxf(m + b2[oc], 0.f);
    }
}

// ============================ quantum gates (compile-time unrolled) ============================
template<int B>
DEV void ry_b(float* sr, float* si, float c, float s) {
    #pragma unroll
    for (int i = 0; i < 16; ++i) if (!(i & B)) {
        int j = i | B;
        float r0 = sr[i], m0 = si[i], r1 = sr[j], m1 = si[j];
        sr[i] = c * r0 - s * r1;  si[i] = c * m0 - s * m1;
        sr[j] = s * r0 + c * r1;  si[j] = s * m0 + c * m1;
    }
}
template<int B>
DEV void rz_b(float* sr, float* si, float c, float s) {
    #pragma unroll
    for (int i = 0; i < 16; ++i) {
        float xr = sr[i], xi = si[i];
        if (!(i & B)) { sr[i] = c * xr + s * xi;  si[i] = c * xi - s * xr; }
        else          { sr[i] = c * xr - s * xi;  si[i] = c * xi + s * xr; }
    }
}
template<int BC, int BT>
DEV void cnot_b(float* sr, float* si) {
    #pragma unroll
    for (int i = 0; i < 16; ++i) if ((i & BC) && !(i & BT)) {
        int j = i | BT;
        float tr = sr[i]; sr[i] = sr[j]; sr[j] = tr;
        float ti = si[i]; si[i] = si[j]; si[j] = ti;
    }
}
template<int A, int Bw>
DEV void ansatz(float* sr, float* si, const float* cc, const float* ss) {
    constexpr int BA = 8 >> A, BB = 8 >> Bw;
    ry_b<BA>(sr, si, cc[0], ss[0]);
    rz_b<BA>(sr, si, cc[1], ss[1]);
    ry_b<BB>(sr, si, cc[2], ss[2]);
    rz_b<BB>(sr, si, cc[3], ss[3]);
    cnot_b<BA, BB>(sr, si);
    ry_b<BA>(sr, si, cc[4], ss[4]);
    rz_b<BA>(sr, si, cc[5], ss[5]);
    ry_b<BB>(sr, si, cc[6], ss[6]);
}

// ============================ conv3 + leaky + sigmoid + quantum circuit ============================
__global__ __launch_bounds__(256) void qconv_kernel(
    const float* __restrict__ out2, const float* __restrict__ w3,
    const float* __restrict__ b3, const float* __restrict__ qp,
    float* __restrict__ q)
{
    int gid = blockIdx.x * 256 + threadIdx.x;   // 392*256 = 100352 exactly
    int n = gid / 49, pp = gid % 49;
    int py = pp / 7, px = pp % 7;
    const float* in = out2 + n * 784;

    float acc[4] = { b3[0], b3[1], b3[2], b3[3] };
    for (int ic = 0; ic < 16; ++ic) {
        #pragma unroll
        for (int ky = 0; ky < 3; ++ky) {
            int yy = py + ky - 1;
            int yc = min(max(yy, 0), 6);
            #pragma unroll
            for (int kx = 0; kx < 3; ++kx) {
                int xx = px + kx - 1;
                int xc = min(max(xx, 0), 6);
                bool valid = ((unsigned)yy < 7u) && ((unsigned)xx < 7u);
                float v = in[ic * 49 + yc * 7 + xc];
                v = valid ? v : 0.f;
                #pragma unroll
                for (int c = 0; c < 4; ++c)
                    acc[c] = fmaf(w3[(c * 16 + ic) * 9 + ky * 3 + kx], v, acc[c]);
            }
        }
    }
    float h[4];
    #pragma unroll
    for (int c = 0; c < 4; ++c) {
        float z = acc[c];
        z = z > 0.f ? z : 0.01f * z;
        float sg = 1.f / (1.f + __expf(-z));
        h[c] = 1.5707963267948966f * sg;
    }

    float sr[16], si[16];
    #pragma unroll
    for (int i = 0; i < 16; ++i) { sr[i] = 0.f; si[i] = 0.f; }
    sr[0] = 1.f;

    float ce, se;
    __sincosf(h[0], &se, &ce); ry_b<8>(sr, si, ce, se);
    __sincosf(h[1], &se, &ce); ry_b<4>(sr, si, ce, se);
    __sincosf(h[2], &se, &ce); ry_b<2>(sr, si, ce, se);
    __sincosf(h[3], &se, &ce); ry_b<1>(sr, si, ce, se);

    float cs0[7], sn0[7], cs1[7], sn1[7];
    #pragma unroll
    for (int k = 0; k < 7; ++k) {
        __sincosf(qp[k] * 0.5f, &sn0[k], &cs0[k]);
        __sincosf(qp[7 + k] * 0.5f, &sn1[k], &cs1[k]);
    }
    ansatz<0, 1>(sr, si, cs0, sn0);
    ansatz<1, 2>(sr, si, cs0, sn0);
    ansatz<2, 3>(sr, si, cs0, sn0);
    ansatz<3, 0>(sr, si, cs0, sn0);
    ansatz<0, 1>(sr, si, cs1, sn1);
    ansatz<1, 2>(sr, si, cs1, sn1);
    ansatz<2, 3>(sr, si, cs1, sn1);
    ansatz<3, 0>(sr, si, cs1, sn1);

    float p[16];
    #pragma unroll
    for (int i = 0; i < 16; ++i) p[i] = sr[i] * sr[i] + si[i] * si[i];

    float* qo = q + n * 196 + pp * 4;
    #pragma unroll
    for (int w = 0; w < 4; ++w) {
        int B = 8 >> w;
        float e = 0.f;
        #pragma unroll
        for (int i = 0; i < 16; ++i) e += (i & B) ? -p[i] : p[i];
        qo[w] = e;
    }
}

// ============================ fused MLP ============================
__global__ __launch_bounds__(64) void fc_kernel(
    const float* __restrict__ q,
    const float* __restrict__ fc1t, const float* __restrict__ fb1,
    const float* __restrict__ fc2t, const float* __restrict__ fb2,
    const float* __restrict__ fc3t, const float* __restrict__ fb3,
    const float* __restrict__ fc4t, const float* __restrict__ fb4,
    float* __restrict__ out)
{
    __shared__ float qr[196], h1[64], h2[128], h3[64];
    int n = blockIdx.x, t = threadIdx.x;
    for (int i = t; i < 196; i += 64) qr[i] = q[n * 196 + i];
    __syncthreads();
    float a = fb1[t];
    for (int k = 0; k < 196; ++k) a = fmaf(fc1t[k * 64 + t], qr[k], a);
    h1[t] = fmaxf(a, 0.f);
    __syncthreads();
    float a0 = fb2[t], a1 = fb2[t + 64];
    for (int k = 0; k < 64; ++k) {
        float v = h1[k];
        a0 = fmaf(fc2t[k * 128 + t], v, a0);
        a1 = fmaf(fc2t[k * 128 + t + 64], v, a1);
    }
    h2[t] = a0; h2[t + 64] = a1;
    __syncthreads();
    a = fb3[t];
    for (int k = 0; k < 128; ++k) a = fmaf(fc3t[k * 64 + t], h2[k], a);
    h3[t] = fmaxf(a, 0.f);
    __syncthreads();
    if (t < 10) {
        a = fb4[t];
        for (int k = 0; k < 64; ++k) a = fmaf(fc4t[k * 10 + t], h3[k], a);
        out[n * 10 + t] = a;
    }
}

// ============================ launch ============================
extern "C" void kernel_launch(void* const* d_in, const int* in_sizes, int n_in,
                              void* d_out, int out_size, void* d_ws, size_t ws_size,
                              hipStream_t stream) {
    const float* x      = (const float*)d_in[0];
    const float* c1w    = (const float*)d_in[1];
    const float* c1b    = (const float*)d_in[2];
    const float* c2w    = (const float*)d_in[3];
    const float* c2b    = (const float*)d_in[4];
    const float* c3w    = (const float*)d_in[5];
    const float* c3b    = (const float*)d_in[6];
    const float* qp     = (const float*)d_in[7];
    const float* fc1w   = (const float*)d_in[8];
    const float* fc1b   = (const float*)d_in[9];
    const float* fc2w   = (const float*)d_in[10];
    const float* fc2b   = (const float*)d_in[11];
    const float* fc3w   = (const float*)d_in[12];
    const float* fc3b   = (const float*)d_in[13];
    const float* fc4w   = (const float*)d_in[14];
    const float* fc4b   = (const float*)d_in[15];
    float* out = (float*)d_out;

    float* ws = (float*)d_ws;
    unsigned short* w2b = (unsigned short*)ws;            // 9216 bf16 (4608 float slots)
    float* fc1t = ws + 4608;                              // 12544
    float* fc2t = fc1t + 12544;                           // 8192
    float* fc3t = fc2t + 8192;                            // 8192
    float* fc4t = fc3t + 8192;                            // 640
    unsigned short* out1 = (unsigned short*)(fc4t + 640); // 2048*12544 bf16 (NHWC)
    float* out2 = (float*)(out1 + (size_t)2048 * 12544);  // 2048*784 f32
    float* qbuf = out2 + (size_t)2048 * 784;              // 2048*196 f32

    prep_kernel<<<40, 256, 0, stream>>>(c2w, fc1w, fc2w, fc3w, fc4w,
                                        w2b, fc1t, fc2t, fc3t, fc4t);
    conv1_kernel<<<683, 640, 0, stream>>>(x, c1w, c1b, out1);
    conv2_kernel<<<2048, 256, 0, stream>>>(out1, w2b, c2b, out2);
    qconv_kernel<<<392, 256, 0, stream>>>(out2, c3w, c3b, qp, qbuf);
    fc_kernel<<<2048, 64, 0, stream>>>(qbuf, fc1t, fc1b, fc2t, fc2b,
                                       fc3t, fc3b, fc4t, fc4b, out);
}

// Round 6
// 97.770 us; speedup vs baseline: 1.2062x; 1.2062x over previous
//
#include <hip/hip_runtime.h>
#include <hip/hip_bf16.h>
#include <math.h>

#define DEV __device__ __forceinline__

typedef __attribute__((ext_vector_type(4))) float f32x4;
typedef __attribute__((ext_vector_type(8))) short bf16x8;

DEV unsigned short f2bf(float v) {
    __hip_bfloat16 h = __float2bfloat16(v);
    return *reinterpret_cast<unsigned short*>(&h);
}

// ============================ prep: weight transposes ============================
// w2b: bf16, index i = ((tap*2+kk)*4 + fq)*128 + oc*8 + j  -> W2[oc][kk*32+fq*8+j][tap]
__global__ void prep_kernel(const float* __restrict__ w2,   // (16,64,3,3)
                            const float* __restrict__ fc1w, // (64,196)
                            const float* __restrict__ fc2w, // (128,64)
                            const float* __restrict__ fc3w, // (64,128)
                            const float* __restrict__ fc4w, // (10,64)
                            unsigned short* __restrict__ w2b, // 9216 bf16
                            float* __restrict__ fc1t,        // (196,64)
                            float* __restrict__ fc2t,        // (64,128)
                            float* __restrict__ fc3t,        // (128,64)
                            float* __restrict__ fc4t)        // (64,10)
{
    int t = blockIdx.x * blockDim.x + threadIdx.x;
    int NT = gridDim.x * blockDim.x;
    for (int i = t; i < 9216; i += NT) {
        int j = i & 7, oc = (i >> 3) & 15, fq = (i >> 7) & 3, f = i >> 9;
        int tap = f >> 1, kk = f & 1;
        int ic = kk * 32 + fq * 8 + j;
        w2b[i] = f2bf(w2[(oc * 64 + ic) * 9 + tap]);
    }
    for (int i = t; i < 12544; i += NT) { int j = i / 196, k = i % 196; fc1t[k * 64 + j] = fc1w[i]; }
    for (int i = t; i < 8192;  i += NT) { int j = i / 64,  k = i % 64;  fc2t[k * 128 + j] = fc2w[i]; }
    for (int i = t; i < 8192;  i += NT) { int j = i / 128, k = i % 128; fc3t[k * 64 + j] = fc3w[i]; }
    for (int i = t; i < 640;   i += NT) { int j = i / 64,  k = i % 64;  fc4t[k * 10 + j] = fc4w[i]; }
}

// ============================ fused conv1+pool+conv2+pool ============================
// x:(2048,1,28,28), w1:(64,1,3,3), w2b:(9 taps as 18 K-frags x 16 oc) bf16
//  -> out2:(2048,16,7,7) f32.  One image per block, 256 threads.
// Phase 1 (VALU): conv1+relu+pool at 196 positions (wave w: pos = w*49+lane, lane<49),
//   weights via wave-uniform s_load, results packed bf16 and ds_write_b128 directly
//   into the XOR-swizzled NHWC tile (chunk g -> g ^ (grid&7), same swizzle MFMA undoes).
// Phase 2 (MFMA): 13 M-tiles x 16 oc x K=64 over 9 shifted taps; pre-pool D in LDS; pool.
__global__ __launch_bounds__(256, 3) void conv12_kernel(
    const float* __restrict__ x, const float* __restrict__ w1,
    const float* __restrict__ b1, const unsigned short* __restrict__ w2b,
    const float* __restrict__ b2, float* __restrict__ out2)
{
    __shared__ unsigned short in_l[16384];   // 32 KB swizzled [16x16 grid][64 ic] bf16
    __shared__ float pin[30 * 34];           // zero-padded input image
    float* d_l = (float*)in_l;               // aliased pre-pool buffer [196][17] f32
    int t = threadIdx.x, lane = t & 63, wv = t >> 6;
    int fq = lane >> 4, fr = lane & 15;
    int n = blockIdx.x;

    // B fragments: issue early, latency hides under staging + conv1 (L2-resident)
    bf16x8 bfrag[18];
    const bf16x8* wb = (const bf16x8*)w2b;
    #pragma unroll
    for (int f = 0; f < 18; ++f) bfrag[f] = wb[(f * 4 + fq) * 16 + fr];

    for (int i = t; i < 2048; i += 256) ((f32x4*)in_l)[i] = f32x4{0.f, 0.f, 0.f, 0.f};
    for (int i = t; i < 1020; i += 256) pin[i] = 0.f;
    __syncthreads();
    for (int i = t; i < 784; i += 256) pin[(i / 28 + 1) * 34 + (i % 28) + 1] = x[n * 784 + i];
    __syncthreads();

    // ---------------- phase 1: conv1 + relu + pool -> swizzled LDS ----------------
    if (lane < 49) {
        int pos = wv * 49 + lane;            // 4 waves x 49 = 196 positions
        int py = pos / 14, px = pos - py * 14;

        float p[4][4];
        const float* base = &pin[(2 * py) * 34 + 2 * px];
        #pragma unroll
        for (int dy = 0; dy < 4; ++dy) {
            float2 lo = *reinterpret_cast<const float2*>(base + dy * 34);
            float2 hi = *reinterpret_cast<const float2*>(base + dy * 34 + 2);
            p[dy][0] = lo.x; p[dy][1] = lo.y; p[dy][2] = hi.x; p[dy][3] = hi.y;
        }

        int grid = (py + 1) * 16 + (px + 1);
        unsigned swz = grid & 7;
        char* rowp = (char*)in_l + grid * 128;

        #pragma unroll
        for (int g = 0; g < 8; ++g) {
            unsigned pk0, pk1, pk2, pk3;
            #pragma unroll
            for (int k = 0; k < 8; ++k) {
                const int oc = g * 8 + k;
                const float* wp = w1 + oc * 9;   // wave-uniform -> s_load
                float w0 = wp[0], w1v = wp[1], w2v = wp[2], w3v = wp[3], w4v = wp[4],
                      w5v = wp[5], w6v = wp[6], w7v = wp[7], w8v = wp[8];
                float bb = b1[oc];
                float m = -INFINITY;
                #pragma unroll
                for (int dy = 0; dy < 2; ++dy)
                    #pragma unroll
                    for (int dx = 0; dx < 2; ++dx) {
                        float s = w0 *p[dy][dx]     + w1v*p[dy][dx+1]     + w2v*p[dy][dx+2]
                                + w3v*p[dy+1][dx]   + w4v*p[dy+1][dx+1]   + w5v*p[dy+1][dx+2]
                                + w6v*p[dy+2][dx]   + w7v*p[dy+2][dx+1]   + w8v*p[dy+2][dx+2];
                        m = fmaxf(m, s);
                    }
                unsigned u = f2bf(fmaxf(m + bb, 0.f));
                if (k == 0) pk0 = u;            else if (k == 1) pk0 |= u << 16;
                else if (k == 2) pk1 = u;       else if (k == 3) pk1 |= u << 16;
                else if (k == 4) pk2 = u;       else if (k == 5) pk2 |= u << 16;
                else if (k == 6) pk3 = u;       else             pk3 |= u << 16;
            }
            uint4 v; v.x = pk0; v.y = pk1; v.z = pk2; v.w = pk3;
            *reinterpret_cast<uint4*>(rowp + ((g ^ swz) << 4)) = v;   // ds_write_b128
        }
    }
    __syncthreads();

    // ---------------- phase 2: conv2 via MFMA (9 shifted GEMMs) ----------------
    for (int r = 0; r < 4; ++r) {
        int tile = r * 4 + wv;
        bool tv = tile < 13;
        f32x4 acc = {0.f, 0.f, 0.f, 0.f};
        int pd0 = tile * 16 + fq * 4;
        if (tv) {
            int pos = tile * 16 + fr; pos = pos > 195 ? 195 : pos;   // clamp tail tile
            int y = pos / 14, xx = pos - y * 14;
            int g0 = y * 16 + xx;
            int vb = g0 * 128 + fq * 16;
            #pragma unroll
            for (int ky = 0; ky < 3; ++ky)
                #pragma unroll
                for (int kx = 0; kx < 3; ++kx) {
                    int dg = ky * 16 + kx;
                    int msk = ((g0 + dg) & 7) << 4;
                    int lin = vb + dg * 128;
                    bf16x8 a0 = *(const bf16x8*)((const char*)in_l + (lin ^ msk));
                    acc = __builtin_amdgcn_mfma_f32_16x16x32_bf16(a0, bfrag[(ky * 3 + kx) * 2], acc, 0, 0, 0);
                    bf16x8 a1 = *(const bf16x8*)((const char*)in_l + ((lin | 64) ^ msk));
                    acc = __builtin_amdgcn_mfma_f32_16x16x32_bf16(a1, bfrag[(ky * 3 + kx) * 2 + 1], acc, 0, 0, 0);
                }
        }
        __syncthreads();                      // all reads of this round done
        if (tv) {
            #pragma unroll
            for (int reg = 0; reg < 4; ++reg) {
                int pd = pd0 + reg;
                if (pd < 196) d_l[pd * 17 + fr] = acc[reg];
            }
        }
        __syncthreads();                      // writes visible; next round's reads disjoint
    }

    float* op = out2 + (size_t)n * 784;
    for (int i = t; i < 784; i += 256) {
        int oc = i & 15, p7 = i >> 4;
        int y7 = p7 / 7, x7 = p7 % 7;
        int p00 = (2 * y7) * 14 + 2 * x7;
        float m = fmaxf(fmaxf(d_l[p00 * 17 + oc], d_l[(p00 + 1) * 17 + oc]),
                        fmaxf(d_l[(p00 + 14) * 17 + oc], d_l[(p00 + 15) * 17 + oc]));
        op[oc * 49 + p7] = fmaxf(m + b2[oc], 0.f);
    }
}

// ============================ quantum gates (compile-time unrolled) ============================
template<int B>
DEV void ry_b(float* sr, float* si, float c, float s) {
    #pragma unroll
    for (int i = 0; i < 16; ++i) if (!(i & B)) {
        int j = i | B;
        float r0 = sr[i], m0 = si[i], r1 = sr[j], m1 = si[j];
        sr[i] = c * r0 - s * r1;  si[i] = c * m0 - s * m1;
        sr[j] = s * r0 + c * r1;  si[j] = s * m0 + c * m1;
    }
}
template<int B>
DEV void rz_b(float* sr, float* si, float c, float s) {
    #pragma unroll
    for (int i = 0; i < 16; ++i) {
        float xr = sr[i], xi = si[i];
        if (!(i & B)) { sr[i] = c * xr + s * xi;  si[i] = c * xi - s * xr; }
        else          { sr[i] = c * xr - s * xi;  si[i] = c * xi + s * xr; }
    }
}
template<int BC, int BT>
DEV void cnot_b(float* sr, float* si) {
    #pragma unroll
    for (int i = 0; i < 16; ++i) if ((i & BC) && !(i & BT)) {
        int j = i | BT;
        float tr = sr[i]; sr[i] = sr[j]; sr[j] = tr;
        float ti = si[i]; si[i] = si[j]; si[j] = ti;
    }
}
template<int A, int Bw>
DEV void ansatz(float* sr, float* si, const float* cc, const float* ss) {
    constexpr int BA = 8 >> A, BB = 8 >> Bw;
    ry_b<BA>(sr, si, cc[0], ss[0]);
    rz_b<BA>(sr, si, cc[1], ss[1]);
    ry_b<BB>(sr, si, cc[2], ss[2]);
    rz_b<BB>(sr, si, cc[3], ss[3]);
    cnot_b<BA, BB>(sr, si);
    ry_b<BA>(sr, si, cc[4], ss[4]);
    rz_b<BA>(sr, si, cc[5], ss[5]);
    ry_b<BB>(sr, si, cc[6], ss[6]);
}

// ============================ conv3 + leaky + sigmoid + quantum circuit ============================
__global__ __launch_bounds__(256) void qconv_kernel(
    const float* __restrict__ out2, const float* __restrict__ w3,
    const float* __restrict__ b3, const float* __restrict__ qp,
    float* __restrict__ q)
{
    int gid = blockIdx.x * 256 + threadIdx.x;   // 392*256 = 100352 exactly
    int n = gid / 49, pp = gid % 49;
    int py = pp / 7, px = pp % 7;
    const float* in = out2 + n * 784;

    float acc[4] = { b3[0], b3[1], b3[2], b3[3] };
    for (int ic = 0; ic < 16; ++ic) {
        #pragma unroll
        for (int ky = 0; ky < 3; ++ky) {
            int yy = py + ky - 1;
            int yc = min(max(yy, 0), 6);
            #pragma unroll
            for (int kx = 0; kx < 3; ++kx) {
                int xx = px + kx - 1;
                int xc = min(max(xx, 0), 6);
                bool valid = ((unsigned)yy < 7u) && ((unsigned)xx < 7u);
                float v = in[ic * 49 + yc * 7 + xc];
                v = valid ? v : 0.f;
                #pragma unroll
                for (int c = 0; c < 4; ++c)
                    acc[c] = fmaf(w3[(c * 16 + ic) * 9 + ky * 3 + kx], v, acc[c]);
            }
        }
    }
    float h[4];
    #pragma unroll
    for (int c = 0; c < 4; ++c) {
        float z = acc[c];
        z = z > 0.f ? z : 0.01f * z;
        float sg = 1.f / (1.f + __expf(-z));
        h[c] = 1.5707963267948966f * sg;
    }

    float sr[16], si[16];
    #pragma unroll
    for (int i = 0; i < 16; ++i) { sr[i] = 0.f; si[i] = 0.f; }
    sr[0] = 1.f;

    float ce, se;
    __sincosf(h[0], &se, &ce); ry_b<8>(sr, si, ce, se);
    __sincosf(h[1], &se, &ce); ry_b<4>(sr, si, ce, se);
    __sincosf(h[2], &se, &ce); ry_b<2>(sr, si, ce, se);
    __sincosf(h[3], &se, &ce); ry_b<1>(sr, si, ce, se);

    float cs0[7], sn0[7], cs1[7], sn1[7];
    #pragma unroll
    for (int k = 0; k < 7; ++k) {
        __sincosf(qp[k] * 0.5f, &sn0[k], &cs0[k]);
        __sincosf(qp[7 + k] * 0.5f, &sn1[k], &cs1[k]);
    }
    ansatz<0, 1>(sr, si, cs0, sn0);
    ansatz<1, 2>(sr, si, cs0, sn0);
    ansatz<2, 3>(sr, si, cs0, sn0);
    ansatz<3, 0>(sr, si, cs0, sn0);
    ansatz<0, 1>(sr, si, cs1, sn1);
    ansatz<1, 2>(sr, si, cs1, sn1);
    ansatz<2, 3>(sr, si, cs1, sn1);
    ansatz<3, 0>(sr, si, cs1, sn1);

    float p[16];
    #pragma unroll
    for (int i = 0; i < 16; ++i) p[i] = sr[i] * sr[i] + si[i] * si[i];

    float* qo = q + n * 196 + pp * 4;
    #pragma unroll
    for (int w = 0; w < 4; ++w) {
        int B = 8 >> w;
        float e = 0.f;
        #pragma unroll
        for (int i = 0; i < 16; ++i) e += (i & B) ? -p[i] : p[i];
        qo[w] = e;
    }
}

// ============================ fused MLP ============================
__global__ __launch_bounds__(64) void fc_kernel(
    const float* __restrict__ q,
    const float* __restrict__ fc1t, const float* __restrict__ fb1,
    const float* __restrict__ fc2t, const float* __restrict__ fb2,
    const float* __restrict__ fc3t, const float* __restrict__ fb3,
    const float* __restrict__ fc4t, const float* __restrict__ fb4,
    float* __restrict__ out)
{
    __shared__ float qr[196], h1[64], h2[128], h3[64];
    int n = blockIdx.x, t = threadIdx.x;
    for (int i = t; i < 196; i += 64) qr[i] = q[n * 196 + i];
    __syncthreads();
    float a = fb1[t];
    for (int k = 0; k < 196; ++k) a = fmaf(fc1t[k * 64 + t], qr[k], a);
    h1[t] = fmaxf(a, 0.f);
    __syncthreads();
    float a0 = fb2[t], a1 = fb2[t + 64];
    for (int k = 0; k < 64; ++k) {
        float v = h1[k];
        a0 = fmaf(fc2t[k * 128 + t], v, a0);
        a1 = fmaf(fc2t[k * 128 + t + 64], v, a1);
    }
    h2[t] = a0; h2[t + 64] = a1;
    __syncthreads();
    a = fb3[t];
    for (int k = 0; k < 128; ++k) a = fmaf(fc3t[k * 64 + t], h2[k], a);
    h3[t] = fmaxf(a, 0.f);
    __syncthreads();
    if (t < 10) {
        a = fb4[t];
        for (int k = 0; k < 64; ++k) a = fmaf(fc4t[k * 10 + t], h3[k], a);
        out[n * 10 + t] = a;
    }
}

// ============================ launch ============================
extern "C" void kernel_launch(void* const* d_in, const int* in_sizes, int n_in,
                              void* d_out, int out_size, void* d_ws, size_t ws_size,
                              hipStream_t stream) {
    const float* x      = (const float*)d_in[0];
    const float* c1w    = (const float*)d_in[1];
    const float* c1b    = (const float*)d_in[2];
    const float* c2w    = (const float*)d_in[3];
    const float* c2b    = (const float*)d_in[4];
    const float* c3w    = (const float*)d_in[5];
    const float* c3b    = (const float*)d_in[6];
    const float* qp     = (const float*)d_in[7];
    const float* fc1w   = (const float*)d_in[8];
    const float* fc1b   = (const float*)d_in[9];
    const float* fc2w   = (const float*)d_in[10];
    const float* fc2b   = (const float*)d_in[11];
    const float* fc3w   = (const float*)d_in[12];
    const float* fc3b   = (const float*)d_in[13];
    const float* fc4w   = (const float*)d_in[14];
    const float* fc4b   = (const float*)d_in[15];
    float* out = (float*)d_out;

    float* ws = (float*)d_ws;
    unsigned short* w2b = (unsigned short*)ws;            // 9216 bf16 (4608 float slots)
    float* fc1t = ws + 4608;                              // 12544
    float* fc2t = fc1t + 12544;                           // 8192
    float* fc3t = fc2t + 8192;                            // 8192
    float* fc4t = fc3t + 8192;                            // 640
    float* out2 = fc4t + 640;                             // 2048*784 f32
    float* qbuf = out2 + (size_t)2048 * 784;              // 2048*196 f32

    prep_kernel<<<40, 256, 0, stream>>>(c2w, fc1w, fc2w, fc3w, fc4w,
                                        w2b, fc1t, fc2t, fc3t, fc4t);
    conv12_kernel<<<2048, 256, 0, stream>>>(x, c1w, c1b, w2b, c2b, out2);
    qconv_kernel<<<392, 256, 0, stream>>>(out2, c3w, c3b, qp, qbuf);
    fc_kernel<<<2048, 64, 0, stream>>>(qbuf, fc1t, fc1b, fc2t, fc2b,
                                       fc3t, fc3b, fc4t, fc4b, out);
}

// Round 7
// 70.949 us; speedup vs baseline: 1.6622x; 1.3780x over previous
//
#include <hip/hip_runtime.h>
#include <hip/hip_bf16.h>
#include <math.h>

#define DEV __device__ __forceinline__

typedef __attribute__((ext_vector_type(4))) float f32x4;
typedef __attribute__((ext_vector_type(8))) short bf16x8;

DEV unsigned short f2bf(float v) {
    __hip_bfloat16 h = __float2bfloat16(v);
    return *reinterpret_cast<unsigned short*>(&h);
}
DEV unsigned pk2(float a, float b) {          // RNE pack 2xf32 -> 2xbf16 (v_cvt_pk)
    union { __hip_bfloat162 b2; unsigned u; } cv;
    cv.b2 = __float22bfloat162_rn(float2{a, b});
    return cv.u;
}

// ============================ prep: weight transposes ============================
// w2b: bf16, i = ((tap*2+kk)*4 + fq)*128 + oc*8 + j  -> W2[oc][kk*32+fq*8+j][tap]
// w1b: bf16, i = (fq*64 + oc)*8 + j -> (fq*8+j)<9 ? W1[oc][fq*8+j] : 0   (K=32 pad)
__global__ void prep_kernel(const float* __restrict__ w1,   // (64,1,3,3)
                            const float* __restrict__ w2,   // (16,64,3,3)
                            const float* __restrict__ fc1w, // (64,196)
                            const float* __restrict__ fc2w, // (128,64)
                            const float* __restrict__ fc3w, // (64,128)
                            const float* __restrict__ fc4w, // (10,64)
                            unsigned short* __restrict__ w1b, // 2048 bf16
                            unsigned short* __restrict__ w2b, // 9216 bf16
                            float* __restrict__ fc1t,        // (196,64)
                            float* __restrict__ fc2t,        // (64,128)
                            float* __restrict__ fc3t,        // (128,64)
                            float* __restrict__ fc4t)        // (64,10)
{
    int t = blockIdx.x * blockDim.x + threadIdx.x;
    int NT = gridDim.x * blockDim.x;
    for (int i = t; i < 2048; i += NT) {
        int j = i & 7, oc = (i >> 3) & 63, fqq = i >> 9;
        int tap = fqq * 8 + j;
        w1b[i] = tap < 9 ? f2bf(w1[oc * 9 + tap]) : (unsigned short)0;
    }
    for (int i = t; i < 9216; i += NT) {
        int j = i & 7, oc = (i >> 3) & 15, fq = (i >> 7) & 3, f = i >> 9;
        int tap = f >> 1, kk = f & 1;
        int ic = kk * 32 + fq * 8 + j;
        w2b[i] = f2bf(w2[(oc * 64 + ic) * 9 + tap]);
    }
    for (int i = t; i < 12544; i += NT) { int j = i / 196, k = i % 196; fc1t[k * 64 + j] = fc1w[i]; }
    for (int i = t; i < 8192;  i += NT) { int j = i / 64,  k = i % 64;  fc2t[k * 128 + j] = fc2w[i]; }
    for (int i = t; i < 8192;  i += NT) { int j = i / 128, k = i % 128; fc3t[k * 64 + j] = fc3w[i]; }
    for (int i = t; i < 640;   i += NT) { int j = i / 64,  k = i % 64;  fc4t[k * 10 + j] = fc4w[i]; }
}

// ============================ fused conv1+pool+conv2+pool (both MFMA) ============================
// Phase 1: conv1 as GEMM [784 m x K32] x [K32 x 64 oc], m = pooled*4 + sub(dy,dx):
//   D row=fq*4+reg -> lane holds all 4 pre-pool subs of pooled=tile*4+fq -> in-lane pool,
//   bf16 results written into XOR-swizzled NHWC tile. K padded 9->32 with ZERO B (A garbage ok).
// Phase 2: conv2 as 9 shifted GEMMs (unchanged).
__global__ __launch_bounds__(256, 3) void conv12_kernel(
    const float* __restrict__ x,
    const float* __restrict__ b1, const unsigned short* __restrict__ w1b,
    const unsigned short* __restrict__ w2b,
    const float* __restrict__ b2, float* __restrict__ out2)
{
    __shared__ __align__(128) char lds_all[36864];
    float* pin = (float*)lds_all;                         // [30][34] f32 zero-padded image
    char* in_b = lds_all + 4096;                          // 32 KB swizzled [256 grid][64 ch] bf16
    float* d_l = (float*)in_b;                            // aliased pre-pool [196][17] f32
    int t = threadIdx.x, lane = t & 63, wv = t >> 6;
    int fq = lane >> 4, fr = lane & 15;
    int n = blockIdx.x;

    // conv2 B fragments (L2-resident)
    bf16x8 bfrag[18];
    const bf16x8* wb = (const bf16x8*)w2b;
    #pragma unroll
    for (int f = 0; f < 18; ++f) bfrag[f] = wb[(f * 4 + fq) * 16 + fr];
    // conv1 B fragments + bias
    bf16x8 w1f[4];
    const bf16x8* wb1 = (const bf16x8*)w1b;
    float b1v[4];
    #pragma unroll
    for (int nt = 0; nt < 4; ++nt) {
        w1f[nt] = wb1[fq * 64 + nt * 16 + fr];
        b1v[nt] = b1[nt * 16 + fr];
    }

    for (int i = t; i < 2048; i += 256) ((f32x4*)in_b)[i] = f32x4{0.f, 0.f, 0.f, 0.f};
    for (int i = t; i < 1020; i += 256) pin[i] = 0.f;
    __syncthreads();
    for (int i = t; i < 784; i += 256) pin[(i / 28 + 1) * 34 + (i % 28) + 1] = x[n * 784 + i];
    __syncthreads();

    // ---------------- phase 1: conv1 via MFMA + in-lane pool ----------------
    for (int tile = wv; tile < 49; tile += 4) {
        // A-frag: row m = tile*16+fr = pooled*4+sub; k = fq*8+j (taps 0..8 real, rest x0)
        int pooledA = tile * 4 + (fr >> 2);
        int pyA = pooledA / 14, pxA = pooledA - pyA * 14;
        int Y = 2 * pyA + ((fr >> 1) & 1), X = 2 * pxA + (fr & 1);
        const float* ap = pin + Y * 34 + X + (fq == 1 ? 70 : 0);  // fq=1: j0 = tap8 @(+2,+2)
        float q0 = ap[0],  q1 = ap[1],  q2 = ap[2];
        float q3 = ap[34], q4 = ap[35], q5 = ap[36];
        float q6 = ap[68], q7 = ap[69];
        union { uint4 u; bf16x8 v; } A;
        A.u.x = pk2(q0, q1); A.u.y = pk2(q2, q3);
        A.u.z = pk2(q4, q5); A.u.w = pk2(q6, q7);

        f32x4 a0 = {0.f,0.f,0.f,0.f}, a1 = {0.f,0.f,0.f,0.f},
              a2 = {0.f,0.f,0.f,0.f}, a3 = {0.f,0.f,0.f,0.f};
        a0 = __builtin_amdgcn_mfma_f32_16x16x32_bf16(A.v, w1f[0], a0, 0, 0, 0);
        a1 = __builtin_amdgcn_mfma_f32_16x16x32_bf16(A.v, w1f[1], a1, 0, 0, 0);
        a2 = __builtin_amdgcn_mfma_f32_16x16x32_bf16(A.v, w1f[2], a2, 0, 0, 0);
        a3 = __builtin_amdgcn_mfma_f32_16x16x32_bf16(A.v, w1f[3], a3, 0, 0, 0);

        // lane holds 4 subs of pooled = tile*4+fq for oc = nt*16+fr
        int pooledD = tile * 4 + fq;
        int pyD = pooledD / 14, pxD = pooledD - pyD * 14;
        int grid = (pyD + 1) * 16 + (pxD + 1);
        unsigned swz = (unsigned)(grid & 7) << 4;
        unsigned base = (unsigned)grid * 128 + (unsigned)fr * 2;
        float v0 = fmaxf(fmaxf(fmaxf(a0[0], a0[1]), fmaxf(a0[2], a0[3])) + b1v[0], 0.f);
        float v1 = fmaxf(fmaxf(fmaxf(a1[0], a1[1]), fmaxf(a1[2], a1[3])) + b1v[1], 0.f);
        float v2 = fmaxf(fmaxf(fmaxf(a2[0], a2[1]), fmaxf(a2[2], a2[3])) + b1v[2], 0.f);
        float v3 = fmaxf(fmaxf(fmaxf(a3[0], a3[1]), fmaxf(a3[2], a3[3])) + b1v[3], 0.f);
        unsigned p01 = pk2(v0, v1), p23 = pk2(v2, v3);
        *(unsigned short*)(in_b + ((base +  0) ^ swz)) = (unsigned short)p01;
        *(unsigned short*)(in_b + ((base + 32) ^ swz)) = (unsigned short)(p01 >> 16);
        *(unsigned short*)(in_b + ((base + 64) ^ swz)) = (unsigned short)p23;
        *(unsigned short*)(in_b + ((base + 96) ^ swz)) = (unsigned short)(p23 >> 16);
    }
    __syncthreads();

    // ---------------- phase 2: conv2 via MFMA (9 shifted GEMMs) ----------------
    for (int r = 0; r < 4; ++r) {
        int tile = r * 4 + wv;
        bool tv = tile < 13;
        f32x4 acc = {0.f, 0.f, 0.f, 0.f};
        int pd0 = tile * 16 + fq * 4;
        if (tv) {
            int pos = tile * 16 + fr; pos = pos > 195 ? 195 : pos;   // clamp tail tile
            int y = pos / 14, xx = pos - y * 14;
            int g0 = y * 16 + xx;
            int vb = g0 * 128 + fq * 16;
            #pragma unroll
            for (int ky = 0; ky < 3; ++ky)
                #pragma unroll
                for (int kx = 0; kx < 3; ++kx) {
                    int dg = ky * 16 + kx;
                    int msk = ((g0 + dg) & 7) << 4;
                    int lin = vb + dg * 128;
                    bf16x8 a0 = *(const bf16x8*)(in_b + (lin ^ msk));
                    acc = __builtin_amdgcn_mfma_f32_16x16x32_bf16(a0, bfrag[(ky * 3 + kx) * 2], acc, 0, 0, 0);
                    bf16x8 a1 = *(const bf16x8*)(in_b + ((lin | 64) ^ msk));
                    acc = __builtin_amdgcn_mfma_f32_16x16x32_bf16(a1, bfrag[(ky * 3 + kx) * 2 + 1], acc, 0, 0, 0);
                }
        }
        __syncthreads();                      // all reads of this round done
        if (tv) {
            #pragma unroll
            for (int reg = 0; reg < 4; ++reg) {
                int pd = pd0 + reg;
                if (pd < 196) d_l[pd * 17 + fr] = acc[reg];
            }
        }
        __syncthreads();                      // writes visible; next round's reads disjoint
    }

    float* op = out2 + (size_t)n * 784;
    for (int i = t; i < 784; i += 256) {
        int oc = i & 15, p7 = i >> 4;
        int y7 = p7 / 7, x7 = p7 % 7;
        int p00 = (2 * y7) * 14 + 2 * x7;
        float m = fmaxf(fmaxf(d_l[p00 * 17 + oc], d_l[(p00 + 1) * 17 + oc]),
                        fmaxf(d_l[(p00 + 14) * 17 + oc], d_l[(p00 + 15) * 17 + oc]));
        op[oc * 49 + p7] = fmaxf(m + b2[oc], 0.f);
    }
}

// ============================ quantum gates (compile-time unrolled) ============================
template<int B>
DEV void ry_b(float* sr, float* si, float c, float s) {
    #pragma unroll
    for (int i = 0; i < 16; ++i) if (!(i & B)) {
        int j = i | B;
        float r0 = sr[i], m0 = si[i], r1 = sr[j], m1 = si[j];
        sr[i] = c * r0 - s * r1;  si[i] = c * m0 - s * m1;
        sr[j] = s * r0 + c * r1;  si[j] = s * m0 + c * m1;
    }
}
template<int B>
DEV void rz_b(float* sr, float* si, float c, float s) {
    #pragma unroll
    for (int i = 0; i < 16; ++i) {
        float xr = sr[i], xi = si[i];
        if (!(i & B)) { sr[i] = c * xr + s * xi;  si[i] = c * xi - s * xr; }
        else          { sr[i] = c * xr - s * xi;  si[i] = c * xi + s * xr; }
    }
}
template<int BC, int BT>
DEV void cnot_b(float* sr, float* si) {
    #pragma unroll
    for (int i = 0; i < 16; ++i) if ((i & BC) && !(i & BT)) {
        int j = i | BT;
        float tr = sr[i]; sr[i] = sr[j]; sr[j] = tr;
        float ti = si[i]; si[i] = si[j]; si[j] = ti;
    }
}
template<int A, int Bw>
DEV void ansatz(float* sr, float* si, const float* cc, const float* ss) {
    constexpr int BA = 8 >> A, BB = 8 >> Bw;
    ry_b<BA>(sr, si, cc[0], ss[0]);
    rz_b<BA>(sr, si, cc[1], ss[1]);
    ry_b<BB>(sr, si, cc[2], ss[2]);
    rz_b<BB>(sr, si, cc[3], ss[3]);
    cnot_b<BA, BB>(sr, si);
    ry_b<BA>(sr, si, cc[4], ss[4]);
    rz_b<BA>(sr, si, cc[5], ss[5]);
    ry_b<BB>(sr, si, cc[6], ss[6]);
}

// ============================ conv3 + leaky + sigmoid + quantum circuit ============================
__global__ __launch_bounds__(256) void qconv_kernel(
    const float* __restrict__ out2, const float* __restrict__ w3,
    const float* __restrict__ b3, const float* __restrict__ qp,
    float* __restrict__ q)
{
    int gid = blockIdx.x * 256 + threadIdx.x;   // 392*256 = 100352 exactly
    int n = gid / 49, pp = gid % 49;
    int py = pp / 7, px = pp % 7;
    const float* in = out2 + n * 784;

    float acc[4] = { b3[0], b3[1], b3[2], b3[3] };
    for (int ic = 0; ic < 16; ++ic) {
        #pragma unroll
        for (int ky = 0; ky < 3; ++ky) {
            int yy = py + ky - 1;
            int yc = min(max(yy, 0), 6);
            #pragma unroll
            for (int kx = 0; kx < 3; ++kx) {
                int xx = px + kx - 1;
                int xc = min(max(xx, 0), 6);
                bool valid = ((unsigned)yy < 7u) && ((unsigned)xx < 7u);
                float v = in[ic * 49 + yc * 7 + xc];
                v = valid ? v : 0.f;
                #pragma unroll
                for (int c = 0; c < 4; ++c)
                    acc[c] = fmaf(w3[(c * 16 + ic) * 9 + ky * 3 + kx], v, acc[c]);
            }
        }
    }
    float h[4];
    #pragma unroll
    for (int c = 0; c < 4; ++c) {
        float z = acc[c];
        z = z > 0.f ? z : 0.01f * z;
        float sg = 1.f / (1.f + __expf(-z));
        h[c] = 1.5707963267948966f * sg;
    }

    float sr[16], si[16];
    #pragma unroll
    for (int i = 0; i < 16; ++i) { sr[i] = 0.f; si[i] = 0.f; }
    sr[0] = 1.f;

    float ce, se;
    __sincosf(h[0], &se, &ce); ry_b<8>(sr, si, ce, se);
    __sincosf(h[1], &se, &ce); ry_b<4>(sr, si, ce, se);
    __sincosf(h[2], &se, &ce); ry_b<2>(sr, si, ce, se);
    __sincosf(h[3], &se, &ce); ry_b<1>(sr, si, ce, se);

    float cs0[7], sn0[7], cs1[7], sn1[7];
    #pragma unroll
    for (int k = 0; k < 7; ++k) {
        __sincosf(qp[k] * 0.5f, &sn0[k], &cs0[k]);
        __sincosf(qp[7 + k] * 0.5f, &sn1[k], &cs1[k]);
    }
    ansatz<0, 1>(sr, si, cs0, sn0);
    ansatz<1, 2>(sr, si, cs0, sn0);
    ansatz<2, 3>(sr, si, cs0, sn0);
    ansatz<3, 0>(sr, si, cs0, sn0);
    ansatz<0, 1>(sr, si, cs1, sn1);
    ansatz<1, 2>(sr, si, cs1, sn1);
    ansatz<2, 3>(sr, si, cs1, sn1);
    ansatz<3, 0>(sr, si, cs1, sn1);

    float p[16];
    #pragma unroll
    for (int i = 0; i < 16; ++i) p[i] = sr[i] * sr[i] + si[i] * si[i];

    float* qo = q + n * 196 + pp * 4;
    #pragma unroll
    for (int w = 0; w < 4; ++w) {
        int B = 8 >> w;
        float e = 0.f;
        #pragma unroll
        for (int i = 0; i < 16; ++i) e += (i & B) ? -p[i] : p[i];
        qo[w] = e;
    }
}

// ============================ fused MLP ============================
__global__ __launch_bounds__(64) void fc_kernel(
    const float* __restrict__ q,
    const float* __restrict__ fc1t, const float* __restrict__ fb1,
    const float* __restrict__ fc2t, const float* __restrict__ fb2,
    const float* __restrict__ fc3t, const float* __restrict__ fb3,
    const float* __restrict__ fc4t, const float* __restrict__ fb4,
    float* __restrict__ out)
{
    __shared__ float qr[196], h1[64], h2[128], h3[64];
    int n = blockIdx.x, t = threadIdx.x;
    for (int i = t; i < 196; i += 64) qr[i] = q[n * 196 + i];
    __syncthreads();
    float a = fb1[t];
    for (int k = 0; k < 196; ++k) a = fmaf(fc1t[k * 64 + t], qr[k], a);
    h1[t] = fmaxf(a, 0.f);
    __syncthreads();
    float a0 = fb2[t], a1 = fb2[t + 64];
    for (int k = 0; k < 64; ++k) {
        float v = h1[k];
        a0 = fmaf(fc2t[k * 128 + t], v, a0);
        a1 = fmaf(fc2t[k * 128 + t + 64], v, a1);
    }
    h2[t] = a0; h2[t + 64] = a1;
    __syncthreads();
    a = fb3[t];
    for (int k = 0; k < 128; ++k) a = fmaf(fc3t[k * 64 + t], h2[k], a);
    h3[t] = fmaxf(a, 0.f);
    __syncthreads();
    if (t < 10) {
        a = fb4[t];
        for (int k = 0; k < 64; ++k) a = fmaf(fc4t[k * 10 + t], h3[k], a);
        out[n * 10 + t] = a;
    }
}

// ============================ launch ============================
extern "C" void kernel_launch(void* const* d_in, const int* in_sizes, int n_in,
                              void* d_out, int out_size, void* d_ws, size_t ws_size,
                              hipStream_t stream) {
    const float* x      = (const float*)d_in[0];
    const float* c1w    = (const float*)d_in[1];
    const float* c1b    = (const float*)d_in[2];
    const float* c2w    = (const float*)d_in[3];
    const float* c2b    = (const float*)d_in[4];
    const float* c3w    = (const float*)d_in[5];
    const float* c3b    = (const float*)d_in[6];
    const float* qp     = (const float*)d_in[7];
    const float* fc1w   = (const float*)d_in[8];
    const float* fc1b   = (const float*)d_in[9];
    const float* fc2w   = (const float*)d_in[10];
    const float* fc2b   = (const float*)d_in[11];
    const float* fc3w   = (const float*)d_in[12];
    const float* fc3b   = (const float*)d_in[13];
    const float* fc4w   = (const float*)d_in[14];
    const float* fc4b   = (const float*)d_in[15];
    float* out = (float*)d_out;

    float* ws = (float*)d_ws;
    unsigned short* w2b = (unsigned short*)ws;            // 9216 bf16 (4608 float slots)
    unsigned short* w1b = (unsigned short*)(ws + 4608);   // 2048 bf16 (1024 float slots)
    float* fc1t = ws + 5632;                              // 12544
    float* fc2t = fc1t + 12544;                           // 8192
    float* fc3t = fc2t + 8192;                            // 8192
    float* fc4t = fc3t + 8192;                            // 640
    float* out2 = fc4t + 640;                             // 2048*784 f32
    float* qbuf = out2 + (size_t)2048 * 784;              // 2048*196 f32

    prep_kernel<<<40, 256, 0, stream>>>(c1w, c2w, fc1w, fc2w, fc3w, fc4w,
                                        w1b, w2b, fc1t, fc2t, fc3t, fc4t);
    conv12_kernel<<<2048, 256, 0, stream>>>(x, c1b, w1b, w2b, c2b, out2);
    qconv_kernel<<<392, 256, 0, stream>>>(out2, c3w, c3b, qp, qbuf);
    fc_kernel<<<2048, 64, 0, stream>>>(qbuf, fc1t, fc1b, fc2t, fc2b,
                                       fc3t, fc3b, fc4t, fc4b, out);
}